// Round 17
// baseline (159.956 us; speedup 1.0000x reference)
//
#include <hip/hip_runtime.h>
#include <hip/hip_bf16.h>
#include <stdint.h>

typedef __attribute__((ext_vector_type(8))) __bf16 bf16x8;
typedef __attribute__((ext_vector_type(4))) float f32x4;
typedef __attribute__((ext_vector_type(4))) unsigned int u32x4;
typedef __attribute__((ext_vector_type(4))) unsigned short u16x4;

#define SEQ 1024
#define DM 1024

#if __has_builtin(__builtin_amdgcn_exp2f)
#define EXP2(x) __builtin_amdgcn_exp2f(x)
#else
#define EXP2(x) exp2f(x)
#endif

typedef __attribute__((address_space(3))) void lds_t;
typedef __attribute__((address_space(1))) void glb_t;

__device__ __forceinline__ unsigned short f2bf(float f){
  __hip_bfloat16 h = __float2bfloat16(f);
  return __builtin_bit_cast(unsigned short, h);
}
__device__ __forceinline__ bf16x8 ld16(const unsigned short* p){
  u32x4 v = *(const u32x4*)p;
  return __builtin_bit_cast(bf16x8, v);
}
__device__ __forceinline__ void gload_lds16(const unsigned short* g, unsigned short* l){
  __builtin_amdgcn_global_load_lds((const glb_t*)g, (lds_t*)l, 16, 0, 0);
}

// ---------------- fp32 -> bf16 convert (x activations) ----------------------
__global__ void cvt_f32_bf16(const float* __restrict__ in,
                             unsigned short* __restrict__ out, int n)
{
  int i = (blockIdx.x * blockDim.x + threadIdx.x) * 8;
  if (i >= n) return;
  float4 a = *(const float4*)(in + i);
  float4 b = *(const float4*)(in + i + 4);
  unsigned short v[8] = { f2bf(a.x), f2bf(a.y), f2bf(a.z), f2bf(a.w),
                          f2bf(b.x), f2bf(b.y), f2bf(b.z), f2bf(b.w) };
  *(u32x4*)(out + i) = *(u32x4*)v;
}

// -------- fp32 weights: [R][C] -> bf16 [C][R] (convert + transpose) ---------
__global__ void transpose_cvt(const float* __restrict__ in,
                              unsigned short* __restrict__ out, int R, int C)
{
  __shared__ unsigned short t[32][33];
  int x  = blockIdx.x * 32 + threadIdx.x;
  int y0 = blockIdx.y * 32 + threadIdx.y;
#pragma unroll
  for (int i = 0; i < 32; i += 8)
    t[threadIdx.y + i][threadIdx.x] = f2bf(in[(size_t)(y0 + i) * C + x]);
  __syncthreads();
  int ox  = blockIdx.y * 32 + threadIdx.x;   // original row
  int oy0 = blockIdx.x * 32 + threadIdx.y;   // original col
#pragma unroll
  for (int i = 0; i < 32; i += 8)
    out[(size_t)(oy0 + i) * R + ox] = t[threadIdx.x][threadIdx.y + i];
}

// ------- QKV GEMM: 256x256 tile, BK=32, 512 thr (8 waves 2Mx4N), 4 buffers --
// m201-style phase choreography: per K-tile two phases, each
//   {ds_read subtile; issue 1 half-stage(t+2); s_barrier; lgkmcnt(0);
//    setprio(1); 16 MFMA; setprio(0); s_barrier}
// counted vmcnt(4) once per K-tile (end of phase 2): tile t+1's 4 loads
// complete, tile t+2's 4 stay in flight. T2 swizzle -> 0 conflicts.
// Epilogue: Q|K -> qk[b][s][2048] (Q scaled 0.125/ln2), V -> vT[b][h][d][s].
__global__ __launch_bounds__(512, 2)
void gemm_qkv(const unsigned short* __restrict__ A,
              const unsigned short* __restrict__ Bt,
              const float* __restrict__ bias,
              unsigned short* __restrict__ qko, unsigned short* __restrict__ vT,
              int M, int N, int K)
{
  __shared__ unsigned short As[4][256 * 32];   // 4 x 16KB
  __shared__ unsigned short Bs[4][256 * 32];   // 4 x 16KB  (128KB total)
  const int tid = threadIdx.x;
  const int l = tid & 63;
  const int w = tid >> 6;                  // 0..7
  const int wm = w >> 2, wn = w & 3;       // 2M x 4N

  const int nbn = N >> 8;                  // 12
  const int nwg = gridDim.x;               // 384 (mult of 8)
  const int bid = blockIdx.x;
  const int qq  = nwg >> 3;
  const int sb  = (bid & 7) * qq + (bid >> 3);   // XCD-bijective swizzle
  const int bm = sb / nbn, bn = sb % nbn;
  const int row0 = bm << 8, col0 = bn << 8;

  // staging: row = tid>>2 (+128 inst1), chunk tid&3; source chunk
  // pre-swizzled by ((row>>1)&3) = ((tid>>3)&3)   [involution]
  const int rs = tid >> 2;
  const int cS = ((tid & 3) ^ ((tid >> 3) & 3)) * 8;
  const unsigned short* ag = A  + (size_t)(row0 + rs) * K + cS;
  const unsigned short* bg = Bt + (size_t)(col0 + rs) * K + cS;

  auto STAGE_A = [&](int kt, int bi) {
    const unsigned short* a = ag + kt * 32;
    gload_lds16(a,                   &As[bi][w * 512]);
    gload_lds16(a + (size_t)128 * K, &As[bi][4096 + w * 512]);
  };
  auto STAGE_B = [&](int kt, int bi) {
    const unsigned short* b = bg + kt * 32;
    gload_lds16(b,                   &Bs[bi][w * 512]);
    gload_lds16(b + (size_t)128 * K, &Bs[bi][4096 + w * 512]);
  };

  const f32x4 zz = {0.f, 0.f, 0.f, 0.f};
  f32x4 acc[8][4];
#pragma unroll
  for (int m = 0; m < 8; m++)
#pragma unroll
    for (int n = 0; n < 4; n++) acc[m][n] = zz;

  const int c16 = l & 15;
  const int csw = ((l >> 4) * 8) ^ (((l >> 1) & 3) << 3);
  const int NT = K >> 5;                   // 32

  STAGE_A(0, 0); STAGE_B(0, 0);
  STAGE_A(1, 1); STAGE_B(1, 1);
  asm volatile("s_waitcnt vmcnt(4)" ::: "memory");   // tile 0 complete
  __builtin_amdgcn_s_barrier();

  for (int t = 0; t < NT; t++) {
    const int bi = t & 3;
    const int si = (t + 2) & 3;
    const bool stg = (t + 2 < NT);

    // ---- phase 1: quadrant m0-3 x n0-3 ----
    bf16x8 af[4], bfr[4];
#pragma unroll
    for (int m = 0; m < 4; m++)
      af[m] = ld16(&As[bi][(wm * 128 + m * 16 + c16) * 32 + csw]);
#pragma unroll
    for (int n = 0; n < 4; n++)
      bfr[n] = ld16(&Bs[bi][(wn * 64 + n * 16 + c16) * 32 + csw]);
    if (stg) STAGE_A(t + 2, si);
    __builtin_amdgcn_s_barrier();
    asm volatile("s_waitcnt lgkmcnt(0)" ::: "memory");
    __builtin_amdgcn_s_setprio(1);
#pragma unroll
    for (int m = 0; m < 4; m++)
#pragma unroll
      for (int n = 0; n < 4; n++)
        acc[m][n] = __builtin_amdgcn_mfma_f32_16x16x32_bf16(af[m], bfr[n], acc[m][n], 0, 0, 0);
    __builtin_amdgcn_s_setprio(0);
    __builtin_amdgcn_s_barrier();

    // ---- phase 2: quadrant m4-7 x n0-3 (B reused from registers) ----
    bf16x8 af2[4];
#pragma unroll
    for (int m = 0; m < 4; m++)
      af2[m] = ld16(&As[bi][(wm * 128 + (m + 4) * 16 + c16) * 32 + csw]);
    if (stg) STAGE_B(t + 2, si);
    __builtin_amdgcn_s_barrier();
    asm volatile("s_waitcnt lgkmcnt(0)" ::: "memory");
    __builtin_amdgcn_s_setprio(1);
#pragma unroll
    for (int m = 0; m < 4; m++)
#pragma unroll
      for (int n = 0; n < 4; n++)
        acc[m + 4][n] = __builtin_amdgcn_mfma_f32_16x16x32_bf16(af2[m], bfr[n], acc[m + 4][n], 0, 0, 0);
    __builtin_amdgcn_s_setprio(0);
    if (t + 1 < NT) {
      if (stg) asm volatile("s_waitcnt vmcnt(4)" ::: "memory");
      else     asm volatile("s_waitcnt vmcnt(0)" ::: "memory");
    }
    __builtin_amdgcn_s_barrier();
  }

  // epilogue: Q|K -> qk (Q scaled 0.125/ln2), V -> vT[b][h][d][s]
#pragma unroll
  for (int n = 0; n < 4; n++) {
    int col = col0 + wn * 64 + n * 16 + c16;
    float bv = bias[col];
#pragma unroll
    for (int m = 0; m < 8; m++) {
      int rbase = row0 + wm * 128 + m * 16 + (l >> 4) * 4;
      if (col < 2048) {
        float sc = (col < 1024) ? 0.18033688f : 1.0f;
#pragma unroll
        for (int r = 0; r < 4; r++)
          qko[(size_t)(rbase + r) * 2048 + col] = f2bf((acc[m][n][r] + bv) * sc);
      } else {
        int bb = rbase >> 10, s0v = rbase & 1023;
        int hh = (col - 2048) >> 6, dd = (col - 2048) & 63;
        u16x4 pk;
#pragma unroll
        for (int r = 0; r < 4; r++) pk[r] = f2bf(acc[m][n][r] + bv);
        *(u16x4*)(vT + ((size_t)((bb * 16 + hh) * 64 + dd)) * 1024 + s0v) = pk;
      }
    }
  }
}

// ---------------- out GEMM: 128x128 tile, BK=32, 3-buffer counted pipeline --
__global__ __launch_bounds__(256, 3)
void gemm_out(const unsigned short* __restrict__ A,
              const unsigned short* __restrict__ Bt,
              const float* __restrict__ bias,
              float* __restrict__ C, int M, int N, int K)
{
  __shared__ unsigned short Ls[3][2][128 * 32];
  const int tid = threadIdx.x;
  const int l = tid & 63;
  const int w = tid >> 6;

  const int nbn = N >> 7;
  const int nwg = gridDim.x;
  const int bid = blockIdx.x;
  const int qq  = nwg >> 3;
  const int sb  = (bid & 7) * qq + (bid >> 3);
  const int bm = sb / nbn, bn = sb % nbn;
  const int row0 = bm << 7, col0 = bn << 7;

  const int rA = w * 16 + (l >> 2);
  const int cS = ((l & 3) ^ ((l >> 3) & 3)) * 8;
  const unsigned short* ag = A  + (size_t)(row0 + rA) * K + cS;
  const unsigned short* bg = Bt + (size_t)(col0 + rA) * K + cS;

  auto STAGE = [&](int kt, int bi) {
    const unsigned short* a = ag + kt * 32;
    const unsigned short* b = bg + kt * 32;
    gload_lds16(a,                  &Ls[bi][0][w * 512]);
    gload_lds16(a + (size_t)64 * K, &Ls[bi][0][2048 + w * 512]);
    gload_lds16(b,                  &Ls[bi][1][w * 512]);
    gload_lds16(b + (size_t)64 * K, &Ls[bi][1][2048 + w * 512]);
  };

  const int wr = (w >> 1) * 64, wc = (w & 1) * 64;
  const f32x4 zz = {0.f, 0.f, 0.f, 0.f};
  f32x4 acc[4][4];
#pragma unroll
  for (int m = 0; m < 4; m++)
#pragma unroll
    for (int n = 0; n < 4; n++) acc[m][n] = zz;

  const int c16 = l & 15;
  const int csw = ((l >> 4) * 8) ^ (((l >> 1) & 3) << 3);

  const int NT = K >> 5;
  STAGE(0, 0);
  STAGE(1, 1);
  asm volatile("s_waitcnt vmcnt(4)" ::: "memory");
  __builtin_amdgcn_s_barrier();

  int cur = 0, stg = 2;
  for (int kt = 0; kt < NT; kt++) {
    if (kt + 2 < NT) STAGE(kt + 2, stg);

    const unsigned short* La = &Ls[cur][0][0];
    const unsigned short* Lb = &Ls[cur][1][0];
    bf16x8 af[4], bfr[4];
#pragma unroll
    for (int m = 0; m < 4; m++)
      af[m] = ld16(La + (wr + m * 16 + c16) * 32 + csw);
#pragma unroll
    for (int n = 0; n < 4; n++)
      bfr[n] = ld16(Lb + (wc + n * 16 + c16) * 32 + csw);
#pragma unroll
    for (int m = 0; m < 4; m++)
#pragma unroll
      for (int n = 0; n < 4; n++)
        acc[m][n] = __builtin_amdgcn_mfma_f32_16x16x32_bf16(af[m], bfr[n], acc[m][n], 0, 0, 0);

    if (kt + 1 < NT) {
      if (kt + 2 < NT) asm volatile("s_waitcnt vmcnt(4)" ::: "memory");
      else             asm volatile("s_waitcnt vmcnt(0)" ::: "memory");
      __builtin_amdgcn_s_barrier();
    }
    cur = (cur == 2) ? 0 : cur + 1;
    stg = (stg == 2) ? 0 : stg + 1;
  }

#pragma unroll
  for (int n = 0; n < 4; n++) {
    int col = col0 + wc + n * 16 + c16;
    float bv = bias[col];
#pragma unroll
    for (int m = 0; m < 4; m++) {
      int rbase = row0 + wr + m * 16 + (l >> 4) * 4;
#pragma unroll
      for (int r = 0; r < 4; r++)
        C[(size_t)(rbase + r) * N + col] = acc[m][n][r] + bv;
    }
  }
}

// -------- causal flash attention (swapped QK^T, FUSED q-tile pair) ----------
__global__ __launch_bounds__(256, 2)
void attn(const unsigned short* __restrict__ qk,
          const unsigned short* __restrict__ vT,
          unsigned short* __restrict__ ctx)
{
  __shared__ unsigned short Ksh[3][64 * 64];   // [kv][d], XOR-swizzled
  __shared__ unsigned short Ps[4][32 * 64];    // per-wave P slab
  const int tid = threadIdx.x;
  const int l = tid & 63, w = tid >> 6;

  const int lin = blockIdx.x + (blockIdx.y << 2);   // 0..511
  const int xcd = lin & 7;
  const int j   = lin >> 3;                         // 0..63
  const int bh  = xcd * 16 + (j & 15);
  const int bx  = j >> 4;                           // 0..3
  const int b = bh >> 4, h = bh & 15;

  const unsigned short* qbase = qk + (size_t)b * SEQ * 2048;
  const unsigned short* kbase = qbase + 1024 + h * 64;
  const unsigned short* vbase = vT + (size_t)bh * 64 * 1024;
  unsigned short* Psw = Ps[w];
  const int d8 = (l >> 4) * 8;
  const int c16 = l & 15;
  const int r4 = (l >> 4) * 4;
  const int kvr = w * 8 + (l >> 3);
  const int cb  = (l & 7) * 16;

  const int qbA = 7 - bx, qbB = bx;
  const int q0A = qbA * 128 + w * 32, q0B = qbB * 128 + w * 32;
  const int ntA = (qbA + 1) * 2;
  const int kmaxA = (q0A + 31) >> 6, kmaxB = (q0B + 31) >> 6;

  bf16x8 qaA[2][2], qaB[2][2];
#pragma unroll
  for (int qc = 0; qc < 2; qc++)
#pragma unroll
    for (int kg = 0; kg < 2; kg++) {
      qaA[qc][kg] = ld16(qbase + (size_t)(q0A + qc * 16 + c16) * 2048
                               + h * 64 + kg * 32 + d8);
      qaB[qc][kg] = ld16(qbase + (size_t)(q0B + qc * 16 + c16) * 2048
                               + h * 64 + kg * 32 + d8);
    }

  const f32x4 zz = {0.f, 0.f, 0.f, 0.f};
  f32x4 oA[2][4], oB[2][4];
#pragma unroll
  for (int m = 0; m < 2; m++)
#pragma unroll
    for (int n = 0; n < 4; n++) { oA[m][n] = zz; oB[m][n] = zz; }
  float mA[2] = {-1e30f, -1e30f}, lA[2] = {0.f, 0.f};
  float mB[2] = {-1e30f, -1e30f}, lB[2] = {0.f, 0.f};

  auto STAGEK = [&](int t, int bufi) {
#pragma unroll
    for (int i = 0; i < 2; i++) {
      int row = i * 32 + kvr;
      int srcb = cb ^ ((row & 7) << 4);
      gload_lds16(kbase + (size_t)(t * 64 + row) * 2048 + (srcb >> 1),
                  &Ksh[bufi][i * 2048 + w * 512]);
    }
  };

  auto QK = [&](const unsigned short* Kc, bf16x8 (&qa)[2][2], f32x4 (&st)[4][2]) {
    bf16x8 kb[4];
    int bo0 = ((d8) * 2) ^ ((c16 & 7) << 4);
    int bo1 = (((32 + d8)) * 2) ^ ((c16 & 7) << 4);
#pragma unroll
    for (int mt = 0; mt < 4; mt++)
      kb[mt] = ld16(Kc + (mt * 16 + c16) * 64 + (bo0 >> 1));
#pragma unroll
    for (int mt = 0; mt < 4; mt++)
#pragma unroll
      for (int qc = 0; qc < 2; qc++)
        st[mt][qc] = __builtin_amdgcn_mfma_f32_16x16x32_bf16(kb[mt], qa[qc][0], zz, 0, 0, 0);
#pragma unroll
    for (int mt = 0; mt < 4; mt++)
      kb[mt] = ld16(Kc + (mt * 16 + c16) * 64 + (bo1 >> 1));
#pragma unroll
    for (int mt = 0; mt < 4; mt++)
#pragma unroll
      for (int qc = 0; qc < 2; qc++)
        st[mt][qc] = __builtin_amdgcn_mfma_f32_16x16x32_bf16(kb[mt], qa[qc][1], st[mt][qc], 0, 0, 0);
  };

  auto SMPV = [&](f32x4 (&st)[4][2], f32x4 (&o)[2][4], float (&mrun)[2],
                  float (&lrun)[2], int q0, int kvt,
                  bf16x8 (&vb0)[4], bf16x8 (&vb1)[4]) {
    if (kvt * 64 + 63 > q0) {
#pragma unroll
      for (int mt = 0; mt < 4; mt++)
#pragma unroll
        for (int qc = 0; qc < 2; qc++) {
          int qg = q0 + qc * 16 + c16;
#pragma unroll
          for (int r = 0; r < 4; r++) {
            int kvg = kvt * 64 + mt * 16 + r4 + r;
            if (kvg > qg) st[mt][qc][r] = -1e30f;
          }
        }
    }
    float plane[2];
#pragma unroll
    for (int qc = 0; qc < 2; qc++) {
      float mx = -1e30f;
#pragma unroll
      for (int mt = 0; mt < 4; mt++)
#pragma unroll
        for (int r = 0; r < 4; r++) mx = fmaxf(mx, st[mt][qc][r]);
      plane[qc] = mx;
    }
    int defer0 = __all(plane[0] - mrun[0] <= 11.5f);
    int defer1 = __all(plane[1] - mrun[1] <= 11.5f);
    float scq[2] = {1.f, 1.f};
#pragma unroll
    for (int qc = 0; qc < 2; qc++) {
      int defer = qc ? defer1 : defer0;
      if (!defer) {
        float mx = plane[qc];
        mx = fmaxf(mx, __shfl_xor(mx, 16));
        mx = fmaxf(mx, __shfl_xor(mx, 32));
        float mn = fmaxf(mrun[qc], mx);
        scq[qc] = EXP2(mrun[qc] - mn);
        mrun[qc] = mn;
      }
      float mn = mrun[qc];
      float rs = 0.f;
#pragma unroll
      for (int mt = 0; mt < 4; mt++)
#pragma unroll
        for (int r = 0; r < 4; r++) {
          float p = EXP2(st[mt][qc][r] - mn);
          st[mt][qc][r] = p;
          rs += p;
        }
      rs += __shfl_xor(rs, 16);
      rs += __shfl_xor(rs, 32);
      lrun[qc] = lrun[qc] * scq[qc] + rs;
    }
    if (!(defer0 && defer1)) {
#pragma unroll
      for (int m = 0; m < 2; m++)
#pragma unroll
        for (int r = 0; r < 4; r++) {
          float sc = __shfl(scq[m], (l & 48) | (r4 + r));
#pragma unroll
          for (int n = 0; n < 4; n++) o[m][n][r] *= sc;
        }
    }
#pragma unroll
    for (int qc = 0; qc < 2; qc++) {
      int rowl = qc * 16 + c16;
#pragma unroll
      for (int mt = 0; mt < 4; mt++) {
        int byteoff = ((mt * 16 + r4) * 2) ^ ((c16 & 7) << 4);
        u16x4 pk;
#pragma unroll
        for (int r = 0; r < 4; r++) pk[r] = f2bf(st[mt][qc][r]);
        *(u16x4*)(Psw + rowl * 64 + (byteoff >> 1)) = pk;
      }
    }
    bf16x8 pa[2];
    int bo0 = (d8 * 2) ^ ((c16 & 7) << 4);
    int bo1 = ((32 + d8) * 2) ^ ((c16 & 7) << 4);
#pragma unroll
    for (int m = 0; m < 2; m++)
      pa[m] = ld16(Psw + (m * 16 + c16) * 64 + (bo0 >> 1));
#pragma unroll
    for (int m = 0; m < 2; m++)
#pragma unroll
      for (int n = 0; n < 4; n++)
        o[m][n] = __builtin_amdgcn_mfma_f32_16x16x32_bf16(pa[m], vb0[n], o[m][n], 0, 0, 0);
#pragma unroll
    for (int m = 0; m < 2; m++)
      pa[m] = ld16(Psw + (m * 16 + c16) * 64 + (bo1 >> 1));
#pragma unroll
    for (int m = 0; m < 2; m++)
#pragma unroll
      for (int n = 0; n < 4; n++)
        o[m][n] = __builtin_amdgcn_mfma_f32_16x16x32_bf16(pa[m], vb1[n], o[m][n], 0, 0, 0);
  };

  STAGEK(0, 0);
  STAGEK(1, 1);
  asm volatile("s_waitcnt vmcnt(2)" ::: "memory");
  __builtin_amdgcn_s_barrier();

  int bufc = 0;
  for (int kvt = 0; kvt < ntA; kvt++) {
    const int bufn = bufc ? bufc - 1 : 2;       // (kvt+2) % 3
    const bool more = (kvt + 2 < ntA);
    if (more) STAGEK(kvt + 2, bufn);
    const unsigned short* Kc = Ksh[bufc];

    if (kvt <= kmaxA) {
      f32x4 st[4][2];
      QK(Kc, qaA, st);
      bf16x8 vb0[4], vb1[4];
#pragma unroll
      for (int n = 0; n < 4; n++) {
        vb0[n] = ld16(vbase + (size_t)(n * 16 + c16) * 1024 + kvt * 64 + d8);
        vb1[n] = ld16(vbase + (size_t)(n * 16 + c16) * 1024 + kvt * 64 + 32 + d8);
      }
      SMPV(st, oA, mA, lA, q0A, kvt, vb0, vb1);
      if (kvt <= kmaxB) {
        QK(Kc, qaB, st);
        SMPV(st, oB, mB, lB, q0B, kvt, vb0, vb1);
      }
    }

    if (more) asm volatile("s_waitcnt vmcnt(2)" ::: "memory");
    else      asm volatile("s_waitcnt vmcnt(0)" ::: "memory");
    __builtin_amdgcn_s_barrier();
    bufc = (bufc == 2) ? 0 : bufc + 1;
  }

  auto WRITE = [&](f32x4 (&o)[2][4], float (&lrun)[2], int q0) {
    float invq[2];
#pragma unroll
    for (int qc = 0; qc < 2; qc++) invq[qc] = 1.f / lrun[qc];
#pragma unroll
    for (int m = 0; m < 2; m++)
#pragma unroll
      for (int r = 0; r < 4; r++) {
        float inv = __shfl(invq[m], (l & 48) | (r4 + r));
        int qg = q0 + m * 16 + r4 + r;
#pragma unroll
        for (int n = 0; n < 4; n++) {
          int d = n * 16 + c16;
          ctx[(size_t)(b * SEQ + qg) * DM + h * 64 + d] = f2bf(o[m][n][r] * inv);
        }
      }
  };
  WRITE(oA, lA, q0A);
  WRITE(oB, lB, q0B);
}

extern "C" void kernel_launch(void* const* d_in, const int* in_sizes, int n_in,
                              void* d_out, int out_size, void* d_ws, size_t ws_size,
                              hipStream_t stream)
{
  const float* x     = (const float*)d_in[0];
  const float* qkv_w = (const float*)d_in[1];
  const float* qkv_b = (const float*)d_in[2];
  const float* out_w = (const float*)d_in[3];
  const float* out_b = (const float*)d_in[4];

  unsigned short* ws   = (unsigned short*)d_ws;
  unsigned short* xb   = ws;                          // 8192*1024
  unsigned short* wqT  = xb  + (size_t)8192 * 1024;   // 3072*1024
  unsigned short* woT  = wqT + 3072 * 1024;           // 1024*1024
  unsigned short* qkb  = woT + 1024 * 1024;           // 8192*2048 (Q|K)
  unsigned short* vTb  = qkb + (size_t)8192 * 2048;   // 128*64*1024 (V^T)
  unsigned short* ctxb = vTb + (size_t)128 * 64 * 1024; // 8192*1024  (~88 MB total)

  hipLaunchKernelGGL(cvt_f32_bf16, dim3(8192 * 1024 / 8 / 256), dim3(256), 0, stream,
                     x, xb, 8192 * 1024);
  hipLaunchKernelGGL(transpose_cvt, dim3(3072 / 32, 1024 / 32), dim3(32, 8), 0, stream,
                     qkv_w, wqT, 1024, 3072);
  hipLaunchKernelGGL(transpose_cvt, dim3(1024 / 32, 1024 / 32), dim3(32, 8), 0, stream,
                     out_w, woT, 1024, 1024);
  hipLaunchKernelGGL(gemm_qkv, dim3(32 * 12), dim3(512), 0, stream,
                     xb, wqT, qkv_b, qkb, vTb, 8192, 3072, 1024);
  hipLaunchKernelGGL(attn, dim3(4, 128), dim3(256), 0, stream,
                     qkb, vTb, ctxb);
  hipLaunchKernelGGL(gemm_out, dim3(64 * 8), dim3(256), 0, stream,
                     ctxb, woT, out_b, (float*)d_out, 8192, 1024, 1024);
}

// Round 18
// 151.551 us; speedup vs baseline: 1.0555x; 1.0555x over previous
//
#include <hip/hip_runtime.h>
#include <hip/hip_bf16.h>
#include <stdint.h>

typedef __attribute__((ext_vector_type(8))) __bf16 bf16x8;
typedef __attribute__((ext_vector_type(4))) float f32x4;
typedef __attribute__((ext_vector_type(4))) unsigned int u32x4;
typedef __attribute__((ext_vector_type(4))) unsigned short u16x4;

#define SEQ 1024
#define DM 1024

#if __has_builtin(__builtin_amdgcn_exp2f)
#define EXP2(x) __builtin_amdgcn_exp2f(x)
#else
#define EXP2(x) exp2f(x)
#endif

typedef __attribute__((address_space(3))) void lds_t;
typedef __attribute__((address_space(1))) void glb_t;

__device__ __forceinline__ unsigned short f2bf(float f){
  __hip_bfloat16 h = __float2bfloat16(f);
  return __builtin_bit_cast(unsigned short, h);
}
__device__ __forceinline__ bf16x8 ld16(const unsigned short* p){
  u32x4 v = *(const u32x4*)p;
  return __builtin_bit_cast(bf16x8, v);
}
__device__ __forceinline__ void gload_lds16(const unsigned short* g, unsigned short* l){
  __builtin_amdgcn_global_load_lds((const glb_t*)g, (lds_t*)l, 16, 0, 0);
}

// ---------------- fp32 -> bf16 convert (x activations) ----------------------
__global__ void cvt_f32_bf16(const float* __restrict__ in,
                             unsigned short* __restrict__ out, int n)
{
  int i = (blockIdx.x * blockDim.x + threadIdx.x) * 8;
  if (i >= n) return;
  float4 a = *(const float4*)(in + i);
  float4 b = *(const float4*)(in + i + 4);
  unsigned short v[8] = { f2bf(a.x), f2bf(a.y), f2bf(a.z), f2bf(a.w),
                          f2bf(b.x), f2bf(b.y), f2bf(b.z), f2bf(b.w) };
  *(u32x4*)(out + i) = *(u32x4*)v;
}

// -------- fp32 weights: [R][C] -> bf16 [C][R] (convert + transpose) ---------
__global__ void transpose_cvt(const float* __restrict__ in,
                              unsigned short* __restrict__ out, int R, int C)
{
  __shared__ unsigned short t[32][33];
  int x  = blockIdx.x * 32 + threadIdx.x;
  int y0 = blockIdx.y * 32 + threadIdx.y;
#pragma unroll
  for (int i = 0; i < 32; i += 8)
    t[threadIdx.y + i][threadIdx.x] = f2bf(in[(size_t)(y0 + i) * C + x]);
  __syncthreads();
  int ox  = blockIdx.y * 32 + threadIdx.x;   // original row
  int oy0 = blockIdx.x * 32 + threadIdx.y;   // original col
#pragma unroll
  for (int i = 0; i < 32; i += 8)
    out[(size_t)(oy0 + i) * R + ox] = t[threadIdx.x][threadIdx.y + i];
}

// ---------------- bf16 GEMM: C = A[M][K] * Bt[N][K]^T + bias ----------------
// 128x128 tile, BK=32, 256 threads (2x2 waves of 64x64).
// 3-buffer LDS pipeline: stage tile kt+2 during tile kt, boundary waits
// vmcnt(4) (prev tile's loads done, newest 4 stay in flight) + 1 barrier.
// T2 bank swizzle (pre-swizzled global source, involution) -> 0 conflicts.
// MODE 1: QKV split -> qk[b][s][2048] (Q scaled 0.125/ln2) + vT[b][h][d][s]
// MODE 2: fp32 store to C0[M][N]
template <int MODE>
__global__ __launch_bounds__(256, 3)
void gemm_bt(const unsigned short* __restrict__ A,
             const unsigned short* __restrict__ Bt,
             const float* __restrict__ bias,
             void* __restrict__ C0, unsigned short* __restrict__ vT,
             int M, int N, int K)
{
  __shared__ unsigned short Ls[3][2][128 * 32];   // [buf][A|B][row*32+col]
  const int tid = threadIdx.x;
  const int l = tid & 63;
  const int w = tid >> 6;

  const int nbn = N >> 7;
  const int nwg = gridDim.x;
  const int bid = blockIdx.x;
  const int qq  = nwg >> 3;                       // grid % 8 == 0 guaranteed
  const int sb  = (bid & 7) * qq + (bid >> 3);    // XCD-bijective swizzle
  const int bm = sb / nbn, bn = sb % nbn;
  const int row0 = bm << 7, col0 = bn << 7;

  // staging: inst i covers rows i*64 + w*16 + (l>>2); 16B chunk (l&3),
  // source col pre-swizzled by ((row>>1)&3) = ((l>>3)&3)  [involution]
  const int rA = w * 16 + (l >> 2);
  const int cS = ((l & 3) ^ ((l >> 3) & 3)) * 8;
  const unsigned short* ag = A  + (size_t)(row0 + rA) * K + cS;
  const unsigned short* bg = Bt + (size_t)(col0 + rA) * K + cS;

  auto STAGE = [&](int kt, int bi) {
    const unsigned short* a = ag + kt * 32;
    const unsigned short* b = bg + kt * 32;
    gload_lds16(a,                  &Ls[bi][0][w * 512]);
    gload_lds16(a + (size_t)64 * K, &Ls[bi][0][2048 + w * 512]);
    gload_lds16(b,                  &Ls[bi][1][w * 512]);
    gload_lds16(b + (size_t)64 * K, &Ls[bi][1][2048 + w * 512]);
  };

  const int wr = (w >> 1) * 64, wc = (w & 1) * 64;
  const f32x4 zz = {0.f, 0.f, 0.f, 0.f};
  f32x4 acc[4][4];
#pragma unroll
  for (int m = 0; m < 4; m++)
#pragma unroll
    for (int n = 0; n < 4; n++) acc[m][n] = zz;

  // fragment read col: chunk of 8 elems, swizzled by ((row>>1)&3) = ((l>>1)&3)
  const int c16 = l & 15;
  const int csw = ((l >> 4) * 8) ^ (((l >> 1) & 3) << 3);

  const int NT = K >> 5;
  STAGE(0, 0);
  STAGE(1, 1);
  asm volatile("s_waitcnt vmcnt(4)" ::: "memory");
  __builtin_amdgcn_s_barrier();

  int cur = 0, stg = 2;
  for (int kt = 0; kt < NT; kt++) {
    if (kt + 2 < NT) STAGE(kt + 2, stg);

    const unsigned short* La = &Ls[cur][0][0];
    const unsigned short* Lb = &Ls[cur][1][0];
    bf16x8 af[4], bfr[4];
#pragma unroll
    for (int m = 0; m < 4; m++)
      af[m] = ld16(La + (wr + m * 16 + c16) * 32 + csw);
#pragma unroll
    for (int n = 0; n < 4; n++)
      bfr[n] = ld16(Lb + (wc + n * 16 + c16) * 32 + csw);
#pragma unroll
    for (int m = 0; m < 4; m++)
#pragma unroll
      for (int n = 0; n < 4; n++)
        acc[m][n] = __builtin_amdgcn_mfma_f32_16x16x32_bf16(af[m], bfr[n], acc[m][n], 0, 0, 0);

    if (kt + 1 < NT) {
      if (kt + 2 < NT) asm volatile("s_waitcnt vmcnt(4)" ::: "memory");
      else             asm volatile("s_waitcnt vmcnt(0)" ::: "memory");
      __builtin_amdgcn_s_barrier();
    }
    cur = (cur == 2) ? 0 : cur + 1;
    stg = (stg == 2) ? 0 : stg + 1;
  }

#pragma unroll
  for (int n = 0; n < 4; n++) {
    int col = col0 + wc + n * 16 + c16;
    float bv = bias[col];
#pragma unroll
    for (int m = 0; m < 4; m++) {
      int rbase = row0 + wr + m * 16 + (l >> 4) * 4;
      if constexpr (MODE == 2) {
#pragma unroll
        for (int r = 0; r < 4; r++)
          ((float*)C0)[(size_t)(rbase + r) * N + col] = acc[m][n][r] + bv;
      } else {
        if (col < 2048) {   // Q or K -> qk buffer [b][s][2048]
          // Q scaled by 0.125/ln2: softmax runs in exp2 domain
          float sc = (col < 1024) ? 0.18033688f : 1.0f;
#pragma unroll
          for (int r = 0; r < 4; r++)
            ((unsigned short*)C0)[(size_t)(rbase + r) * 2048 + col] =
                f2bf((acc[m][n][r] + bv) * sc);
        } else {            // V -> vT[b][h][d][s], 8B packed along s
          int bb = rbase >> 10, s0v = rbase & 1023;
          int hh = (col - 2048) >> 6, dd = (col - 2048) & 63;
          u16x4 pk;
#pragma unroll
          for (int r = 0; r < 4; r++) pk[r] = f2bf(acc[m][n][r] + bv);
          *(u16x4*)(vT + ((size_t)((bb * 16 + hh) * 64 + dd)) * 1024 + s0v) = pk;
        }
      }
    }
  }
}

// -------- causal flash attention (swapped QK^T, FUSED q-tile pair) ----------
// qk: [b][s][2048] bf16 (Q scaled 0.125/ln2 -> exp2 domain). vT: [b][h][d][s].
// grid (4,128): block processes q-tiles qbA=7-bx and qbB=bx over ONE shared
// K/V stream (ntA tiles). 3-buffer K staging, barrier waits vmcnt(2) (counted).
// Each wave: 2 independent QK->softmax->PV chains on overlap tiles.
__global__ __launch_bounds__(256, 2)
void attn(const unsigned short* __restrict__ qk,
          const unsigned short* __restrict__ vT,
          unsigned short* __restrict__ ctx)
{
  __shared__ unsigned short Ksh[3][64 * 64];   // [kv][d], XOR-swizzled
  __shared__ unsigned short Ps[4][32 * 64];    // per-wave P slab
  const int tid = threadIdx.x;
  const int l = tid & 63, w = tid >> 6;

  // placement: all 4 blocks of a bh on one XCD (K/V L2-local)
  const int lin = blockIdx.x + (blockIdx.y << 2);   // 0..511
  const int xcd = lin & 7;
  const int j   = lin >> 3;                         // 0..63
  const int bh  = xcd * 16 + (j & 15);
  const int bx  = j >> 4;                           // 0..3
  const int b = bh >> 4, h = bh & 15;

  const unsigned short* qbase = qk + (size_t)b * SEQ * 2048;
  const unsigned short* kbase = qbase + 1024 + h * 64;
  const unsigned short* vbase = vT + (size_t)bh * 64 * 1024;
  unsigned short* Psw = Ps[w];
  const int d8 = (l >> 4) * 8;
  const int c16 = l & 15;
  const int r4 = (l >> 4) * 4;
  const int kvr = w * 8 + (l >> 3);
  const int cb  = (l & 7) * 16;

  const int qbA = 7 - bx, qbB = bx;
  const int q0A = qbA * 128 + w * 32, q0B = qbB * 128 + w * 32;
  const int ntA = (qbA + 1) * 2;
  const int kmaxA = (q0A + 31) >> 6, kmaxB = (q0B + 31) >> 6;

  // Q fragments (B-operand)
  bf16x8 qaA[2][2], qaB[2][2];
#pragma unroll
  for (int qc = 0; qc < 2; qc++)
#pragma unroll
    for (int kg = 0; kg < 2; kg++) {
      qaA[qc][kg] = ld16(qbase + (size_t)(q0A + qc * 16 + c16) * 2048
                               + h * 64 + kg * 32 + d8);
      qaB[qc][kg] = ld16(qbase + (size_t)(q0B + qc * 16 + c16) * 2048
                               + h * 64 + kg * 32 + d8);
    }

  const f32x4 zz = {0.f, 0.f, 0.f, 0.f};
  f32x4 oA[2][4], oB[2][4];
#pragma unroll
  for (int m = 0; m < 2; m++)
#pragma unroll
    for (int n = 0; n < 4; n++) { oA[m][n] = zz; oB[m][n] = zz; }
  float mA[2] = {-1e30f, -1e30f}, lA[2] = {0.f, 0.f};
  float mB[2] = {-1e30f, -1e30f}, lB[2] = {0.f, 0.f};

  auto STAGEK = [&](int t, int bufi) {
#pragma unroll
    for (int i = 0; i < 2; i++) {
      int row = i * 32 + kvr;
      int srcb = cb ^ ((row & 7) << 4);
      gload_lds16(kbase + (size_t)(t * 64 + row) * 2048 + (srcb >> 1),
                  &Ksh[bufi][i * 2048 + w * 512]);
    }
  };

  // QK^T: S^T[mt][qc] = K(rows kv) . Q^T(cols q), K from swizzled LDS
  auto QK = [&](const unsigned short* Kc, bf16x8 (&qa)[2][2], f32x4 (&st)[4][2]) {
    bf16x8 kb[4];
    int bo0 = ((d8) * 2) ^ ((c16 & 7) << 4);
    int bo1 = (((32 + d8)) * 2) ^ ((c16 & 7) << 4);
#pragma unroll
    for (int mt = 0; mt < 4; mt++)
      kb[mt] = ld16(Kc + (mt * 16 + c16) * 64 + (bo0 >> 1));
#pragma unroll
    for (int mt = 0; mt < 4; mt++)
#pragma unroll
      for (int qc = 0; qc < 2; qc++)
        st[mt][qc] = __builtin_amdgcn_mfma_f32_16x16x32_bf16(kb[mt], qa[qc][0], zz, 0, 0, 0);
#pragma unroll
    for (int mt = 0; mt < 4; mt++)
      kb[mt] = ld16(Kc + (mt * 16 + c16) * 64 + (bo1 >> 1));
#pragma unroll
    for (int mt = 0; mt < 4; mt++)
#pragma unroll
      for (int qc = 0; qc < 2; qc++)
        st[mt][qc] = __builtin_amdgcn_mfma_f32_16x16x32_bf16(kb[mt], qa[qc][1], st[mt][qc], 0, 0, 0);
  };

  // mask + online softmax (exp2 domain, defer-max) + P-write + PV
  auto SMPV = [&](f32x4 (&st)[4][2], f32x4 (&o)[2][4], float (&mrun)[2],
                  float (&lrun)[2], int q0, int kvt,
                  bf16x8 (&vb0)[4], bf16x8 (&vb1)[4]) {
    if (kvt * 64 + 63 > q0) {
#pragma unroll
      for (int mt = 0; mt < 4; mt++)
#pragma unroll
        for (int qc = 0; qc < 2; qc++) {
          int qg = q0 + qc * 16 + c16;
#pragma unroll
          for (int r = 0; r < 4; r++) {
            int kvg = kvt * 64 + mt * 16 + r4 + r;
            if (kvg > qg) st[mt][qc][r] = -1e30f;
          }
        }
    }
    float plane[2];
#pragma unroll
    for (int qc = 0; qc < 2; qc++) {
      float mx = -1e30f;
#pragma unroll
      for (int mt = 0; mt < 4; mt++)
#pragma unroll
        for (int r = 0; r < 4; r++) mx = fmaxf(mx, st[mt][qc][r]);
      plane[qc] = mx;
    }
    int defer0 = __all(plane[0] - mrun[0] <= 11.5f);
    int defer1 = __all(plane[1] - mrun[1] <= 11.5f);
    float scq[2] = {1.f, 1.f};
#pragma unroll
    for (int qc = 0; qc < 2; qc++) {
      int defer = qc ? defer1 : defer0;
      if (!defer) {
        float mx = plane[qc];
        mx = fmaxf(mx, __shfl_xor(mx, 16));
        mx = fmaxf(mx, __shfl_xor(mx, 32));
        float mn = fmaxf(mrun[qc], mx);
        scq[qc] = EXP2(mrun[qc] - mn);
        mrun[qc] = mn;
      }
      float mn = mrun[qc];
      float rs = 0.f;
#pragma unroll
      for (int mt = 0; mt < 4; mt++)
#pragma unroll
        for (int r = 0; r < 4; r++) {
          float p = EXP2(st[mt][qc][r] - mn);
          st[mt][qc][r] = p;
          rs += p;
        }
      rs += __shfl_xor(rs, 16);
      rs += __shfl_xor(rs, 32);
      lrun[qc] = lrun[qc] * scq[qc] + rs;
    }
    if (!(defer0 && defer1)) {
#pragma unroll
      for (int m = 0; m < 2; m++)
#pragma unroll
        for (int r = 0; r < 4; r++) {
          float sc = __shfl(scq[m], (l & 48) | (r4 + r));
#pragma unroll
          for (int n = 0; n < 4; n++) o[m][n][r] *= sc;
        }
    }
    // P^T -> per-wave slab, packed 8B swizzled stores
#pragma unroll
    for (int qc = 0; qc < 2; qc++) {
      int rowl = qc * 16 + c16;
#pragma unroll
      for (int mt = 0; mt < 4; mt++) {
        int byteoff = ((mt * 16 + r4) * 2) ^ ((c16 & 7) << 4);
        u16x4 pk;
#pragma unroll
        for (int r = 0; r < 4; r++) pk[r] = f2bf(st[mt][qc][r]);
        *(u16x4*)(Psw + rowl * 64 + (byteoff >> 1)) = pk;
      }
    }
    // O += P V
    bf16x8 pa[2];
    int bo0 = (d8 * 2) ^ ((c16 & 7) << 4);
    int bo1 = ((32 + d8) * 2) ^ ((c16 & 7) << 4);
#pragma unroll
    for (int m = 0; m < 2; m++)
      pa[m] = ld16(Psw + (m * 16 + c16) * 64 + (bo0 >> 1));
#pragma unroll
    for (int m = 0; m < 2; m++)
#pragma unroll
      for (int n = 0; n < 4; n++)
        o[m][n] = __builtin_amdgcn_mfma_f32_16x16x32_bf16(pa[m], vb0[n], o[m][n], 0, 0, 0);
#pragma unroll
    for (int m = 0; m < 2; m++)
      pa[m] = ld16(Psw + (m * 16 + c16) * 64 + (bo1 >> 1));
#pragma unroll
    for (int m = 0; m < 2; m++)
#pragma unroll
      for (int n = 0; n < 4; n++)
        o[m][n] = __builtin_amdgcn_mfma_f32_16x16x32_bf16(pa[m], vb1[n], o[m][n], 0, 0, 0);
  };

  STAGEK(0, 0);
  STAGEK(1, 1);
  asm volatile("s_waitcnt vmcnt(2)" ::: "memory");
  __builtin_amdgcn_s_barrier();

  int bufc = 0;
  for (int kvt = 0; kvt < ntA; kvt++) {
    const int bufn = bufc ? bufc - 1 : 2;       // (kvt+2) % 3
    const bool more = (kvt + 2 < ntA);
    if (more) STAGEK(kvt + 2, bufn);
    const unsigned short* Kc = Ksh[bufc];

    if (kvt <= kmaxA) {
      f32x4 st[4][2];
      QK(Kc, qaA, st);
      bf16x8 vb0[4], vb1[4];
#pragma unroll
      for (int n = 0; n < 4; n++) {
        vb0[n] = ld16(vbase + (size_t)(n * 16 + c16) * 1024 + kvt * 64 + d8);
        vb1[n] = ld16(vbase + (size_t)(n * 16 + c16) * 1024 + kvt * 64 + 32 + d8);
      }
      SMPV(st, oA, mA, lA, q0A, kvt, vb0, vb1);
      if (kvt <= kmaxB) {
        QK(Kc, qaB, st);
        SMPV(st, oB, mB, lB, q0B, kvt, vb0, vb1);
      }
    }

    if (more) asm volatile("s_waitcnt vmcnt(2)" ::: "memory");
    else      asm volatile("s_waitcnt vmcnt(0)" ::: "memory");
    __builtin_amdgcn_s_barrier();
    bufc = (bufc == 2) ? 0 : bufc + 1;
  }

  // epilogues: broadcast 1/l into O layout, write ctx [b][s][h*64+d]
  auto WRITE = [&](f32x4 (&o)[2][4], float (&lrun)[2], int q0) {
    float invq[2];
#pragma unroll
    for (int qc = 0; qc < 2; qc++) invq[qc] = 1.f / lrun[qc];
#pragma unroll
    for (int m = 0; m < 2; m++)
#pragma unroll
      for (int r = 0; r < 4; r++) {
        float inv = __shfl(invq[m], (l & 48) | (r4 + r));
        int qg = q0 + m * 16 + r4 + r;
#pragma unroll
        for (int n = 0; n < 4; n++) {
          int d = n * 16 + c16;
          ctx[(size_t)(b * SEQ + qg) * DM + h * 64 + d] = f2bf(o[m][n][r] * inv);
        }
      }
  };
  WRITE(oA, lA, q0A);
  WRITE(oB, lB, q0B);
}

extern "C" void kernel_launch(void* const* d_in, const int* in_sizes, int n_in,
                              void* d_out, int out_size, void* d_ws, size_t ws_size,
                              hipStream_t stream)
{
  const float* x     = (const float*)d_in[0];
  const float* qkv_w = (const float*)d_in[1];
  const float* qkv_b = (const float*)d_in[2];
  const float* out_w = (const float*)d_in[3];
  const float* out_b = (const float*)d_in[4];

  unsigned short* ws   = (unsigned short*)d_ws;
  unsigned short* xb   = ws;                          // 8192*1024
  unsigned short* wqT  = xb  + (size_t)8192 * 1024;   // 3072*1024
  unsigned short* woT  = wqT + 3072 * 1024;           // 1024*1024
  unsigned short* qkb  = woT + 1024 * 1024;           // 8192*2048 (Q|K)
  unsigned short* vTb  = qkb + (size_t)8192 * 2048;   // 128*64*1024 (V^T)
  unsigned short* ctxb = vTb + (size_t)128 * 64 * 1024; // 8192*1024  (~88 MB total)

  hipLaunchKernelGGL(cvt_f32_bf16, dim3(8192 * 1024 / 8 / 256), dim3(256), 0, stream,
                     x, xb, 8192 * 1024);
  hipLaunchKernelGGL(transpose_cvt, dim3(3072 / 32, 1024 / 32), dim3(32, 8), 0, stream,
                     qkv_w, wqT, 1024, 3072);
  hipLaunchKernelGGL(transpose_cvt, dim3(1024 / 32, 1024 / 32), dim3(32, 8), 0, stream,
                     out_w, woT, 1024, 1024);
  hipLaunchKernelGGL(gemm_bt<1>, dim3(64 * 24), dim3(256), 0, stream,
                     xb, wqT, qkv_b, (void*)qkb, vTb, 8192, 3072, 1024);
  hipLaunchKernelGGL(attn, dim3(4, 128), dim3(256), 0, stream,
                     qkb, vTb, ctxb);
  hipLaunchKernelGGL(gemm_bt<2>, dim3(64 * 8), dim3(256), 0, stream,
                     ctxb, woT, out_b, d_out, nullptr, 8192, 1024, 1024);
}

// Round 19
// 150.136 us; speedup vs baseline: 1.0654x; 1.0094x over previous
//
#include <hip/hip_runtime.h>
#include <hip/hip_bf16.h>
#include <stdint.h>

typedef __attribute__((ext_vector_type(8))) __bf16 bf16x8;
typedef __attribute__((ext_vector_type(4))) float f32x4;
typedef __attribute__((ext_vector_type(4))) unsigned int u32x4;
typedef __attribute__((ext_vector_type(4))) unsigned short u16x4;

#define SEQ 1024
#define DM 1024

#if __has_builtin(__builtin_amdgcn_exp2f)
#define EXP2(x) __builtin_amdgcn_exp2f(x)
#else
#define EXP2(x) exp2f(x)
#endif

typedef __attribute__((address_space(3))) void lds_t;
typedef __attribute__((address_space(1))) void glb_t;

__device__ __forceinline__ unsigned short f2bf(float f){
  __hip_bfloat16 h = __float2bfloat16(f);
  return __builtin_bit_cast(unsigned short, h);
}
__device__ __forceinline__ bf16x8 ld16(const unsigned short* p){
  u32x4 v = *(const u32x4*)p;
  return __builtin_bit_cast(bf16x8, v);
}
__device__ __forceinline__ void gload_lds16(const unsigned short* g, unsigned short* l){
  __builtin_amdgcn_global_load_lds((const glb_t*)g, (lds_t*)l, 16, 0, 0);
}

// ---------------- fp32 -> bf16 convert (x activations) ----------------------
__global__ void cvt_f32_bf16(const float* __restrict__ in,
                             unsigned short* __restrict__ out, int n)
{
  int i = (blockIdx.x * blockDim.x + threadIdx.x) * 8;
  if (i >= n) return;
  float4 a = *(const float4*)(in + i);
  float4 b = *(const float4*)(in + i + 4);
  unsigned short v[8] = { f2bf(a.x), f2bf(a.y), f2bf(a.z), f2bf(a.w),
                          f2bf(b.x), f2bf(b.y), f2bf(b.z), f2bf(b.w) };
  *(u32x4*)(out + i) = *(u32x4*)v;
}

// -------- fp32 weights: [R][C] -> bf16 [C][R] (convert + transpose) ---------
__global__ void transpose_cvt(const float* __restrict__ in,
                              unsigned short* __restrict__ out, int R, int C)
{
  __shared__ unsigned short t[32][33];
  int x  = blockIdx.x * 32 + threadIdx.x;
  int y0 = blockIdx.y * 32 + threadIdx.y;
#pragma unroll
  for (int i = 0; i < 32; i += 8)
    t[threadIdx.y + i][threadIdx.x] = f2bf(in[(size_t)(y0 + i) * C + x]);
  __syncthreads();
  int ox  = blockIdx.y * 32 + threadIdx.x;   // original row
  int oy0 = blockIdx.x * 32 + threadIdx.y;   // original col
#pragma unroll
  for (int i = 0; i < 32; i += 8)
    out[(size_t)(oy0 + i) * R + ox] = t[threadIdx.x][threadIdx.y + i];
}

// ---------------- bf16 GEMM: C = A[M][K] * Bt[N][K]^T + bias ----------------
// 128x128 tile, BK=32, 256 threads (2x2 waves of 64x64).
// 3-buffer LDS pipeline: stage tile kt+2 during tile kt, boundary waits
// vmcnt(4) (prev tile's loads done, newest 4 stay in flight) + 1 barrier.
// T2 bank swizzle (pre-swizzled global source, involution) -> 0 conflicts.
// Structural ceiling of this family: LDS-read-BW bound at ~26% MfmaUtil
// (96KB frag reads per CU-K-step vs 230cy MFMA; verified r10/r16/r18).
// MODE 1: QKV split -> qk[b][s][2048] (Q scaled 0.125/ln2) + vT[b][h][d][s]
// MODE 2: fp32 store to C0[M][N]
template <int MODE>
__global__ __launch_bounds__(256, 3)
void gemm_bt(const unsigned short* __restrict__ A,
             const unsigned short* __restrict__ Bt,
             const float* __restrict__ bias,
             void* __restrict__ C0, unsigned short* __restrict__ vT,
             int M, int N, int K)
{
  __shared__ unsigned short Ls[3][2][128 * 32];   // [buf][A|B][row*32+col]
  const int tid = threadIdx.x;
  const int l = tid & 63;
  const int w = tid >> 6;

  const int nbn = N >> 7;
  const int nwg = gridDim.x;
  const int bid = blockIdx.x;
  const int qq  = nwg >> 3;                       // grid % 8 == 0 guaranteed
  const int sb  = (bid & 7) * qq + (bid >> 3);    // XCD-bijective swizzle
  const int bm = sb / nbn, bn = sb % nbn;
  const int row0 = bm << 7, col0 = bn << 7;

  // staging: inst i covers rows i*64 + w*16 + (l>>2); 16B chunk (l&3),
  // source col pre-swizzled by ((row>>1)&3) = ((l>>3)&3)  [involution]
  const int rA = w * 16 + (l >> 2);
  const int cS = ((l & 3) ^ ((l >> 3) & 3)) * 8;
  const unsigned short* ag = A  + (size_t)(row0 + rA) * K + cS;
  const unsigned short* bg = Bt + (size_t)(col0 + rA) * K + cS;

  auto STAGE = [&](int kt, int bi) {
    const unsigned short* a = ag + kt * 32;
    const unsigned short* b = bg + kt * 32;
    gload_lds16(a,                  &Ls[bi][0][w * 512]);
    gload_lds16(a + (size_t)64 * K, &Ls[bi][0][2048 + w * 512]);
    gload_lds16(b,                  &Ls[bi][1][w * 512]);
    gload_lds16(b + (size_t)64 * K, &Ls[bi][1][2048 + w * 512]);
  };

  const int wr = (w >> 1) * 64, wc = (w & 1) * 64;
  const f32x4 zz = {0.f, 0.f, 0.f, 0.f};
  f32x4 acc[4][4];
#pragma unroll
  for (int m = 0; m < 4; m++)
#pragma unroll
    for (int n = 0; n < 4; n++) acc[m][n] = zz;

  // fragment read col: chunk of 8 elems, swizzled by ((row>>1)&3) = ((l>>1)&3)
  const int c16 = l & 15;
  const int csw = ((l >> 4) * 8) ^ (((l >> 1) & 3) << 3);

  const int NT = K >> 5;
  STAGE(0, 0);
  STAGE(1, 1);
  asm volatile("s_waitcnt vmcnt(4)" ::: "memory");
  __builtin_amdgcn_s_barrier();

  int cur = 0, stg = 2;
  for (int kt = 0; kt < NT; kt++) {
    if (kt + 2 < NT) STAGE(kt + 2, stg);

    const unsigned short* La = &Ls[cur][0][0];
    const unsigned short* Lb = &Ls[cur][1][0];
    bf16x8 af[4], bfr[4];
#pragma unroll
    for (int m = 0; m < 4; m++)
      af[m] = ld16(La + (wr + m * 16 + c16) * 32 + csw);
#pragma unroll
    for (int n = 0; n < 4; n++)
      bfr[n] = ld16(Lb + (wc + n * 16 + c16) * 32 + csw);
#pragma unroll
    for (int m = 0; m < 4; m++)
#pragma unroll
      for (int n = 0; n < 4; n++)
        acc[m][n] = __builtin_amdgcn_mfma_f32_16x16x32_bf16(af[m], bfr[n], acc[m][n], 0, 0, 0);

    if (kt + 1 < NT) {
      if (kt + 2 < NT) asm volatile("s_waitcnt vmcnt(4)" ::: "memory");
      else             asm volatile("s_waitcnt vmcnt(0)" ::: "memory");
      __builtin_amdgcn_s_barrier();
    }
    cur = (cur == 2) ? 0 : cur + 1;
    stg = (stg == 2) ? 0 : stg + 1;
  }

#pragma unroll
  for (int n = 0; n < 4; n++) {
    int col = col0 + wc + n * 16 + c16;
    float bv = bias[col];
#pragma unroll
    for (int m = 0; m < 4; m++) {
      int rbase = row0 + wr + m * 16 + (l >> 4) * 4;
      if constexpr (MODE == 2) {
#pragma unroll
        for (int r = 0; r < 4; r++)
          ((float*)C0)[(size_t)(rbase + r) * N + col] = acc[m][n][r] + bv;
      } else {
        if (col < 2048) {   // Q or K -> qk buffer [b][s][2048]
          // Q scaled by 0.125/ln2: softmax runs in exp2 domain
          float sc = (col < 1024) ? 0.18033688f : 1.0f;
#pragma unroll
          for (int r = 0; r < 4; r++)
            ((unsigned short*)C0)[(size_t)(rbase + r) * 2048 + col] =
                f2bf((acc[m][n][r] + bv) * sc);
        } else {            // V -> vT[b][h][d][s], 8B packed along s
          int bb = rbase >> 10, s0v = rbase & 1023;
          int hh = (col - 2048) >> 6, dd = (col - 2048) & 63;
          u16x4 pk;
#pragma unroll
          for (int r = 0; r < 4; r++) pk[r] = f2bf(acc[m][n][r] + bv);
          *(u16x4*)(vT + ((size_t)((bb * 16 + hh) * 64 + dd)) * 1024 + s0v) = pk;
        }
      }
    }
  }
}

// -------- causal flash attention (swapped QK^T, FUSED q-tile pair) ----------
// qk: [b][s][2048] bf16 (Q scaled 0.125/ln2 -> exp2 domain). vT: [b][h][d][s].
// grid (4,128): block processes q-tiles qbA=7-bx and qbB=bx over ONE shared
// K/V stream (ntA tiles). 3-buffer K staging, barrier waits vmcnt(2) (counted).
// Each wave: 2 independent QK->softmax->PV chains on overlap tiles.
__global__ __launch_bounds__(256, 2)
void attn(const unsigned short* __restrict__ qk,
          const unsigned short* __restrict__ vT,
          unsigned short* __restrict__ ctx)
{
  __shared__ unsigned short Ksh[3][64 * 64];   // [kv][d], XOR-swizzled
  __shared__ unsigned short Ps[4][32 * 64];    // per-wave P slab
  const int tid = threadIdx.x;
  const int l = tid & 63, w = tid >> 6;

  // placement: all 4 blocks of a bh on one XCD (K/V L2-local)
  const int lin = blockIdx.x + (blockIdx.y << 2);   // 0..511
  const int xcd = lin & 7;
  const int j   = lin >> 3;                         // 0..63
  const int bh  = xcd * 16 + (j & 15);
  const int bx  = j >> 4;                           // 0..3
  const int b = bh >> 4, h = bh & 15;

  const unsigned short* qbase = qk + (size_t)b * SEQ * 2048;
  const unsigned short* kbase = qbase + 1024 + h * 64;
  const unsigned short* vbase = vT + (size_t)bh * 64 * 1024;
  unsigned short* Psw = Ps[w];
  const int d8 = (l >> 4) * 8;
  const int c16 = l & 15;
  const int r4 = (l >> 4) * 4;
  const int kvr = w * 8 + (l >> 3);
  const int cb  = (l & 7) * 16;

  const int qbA = 7 - bx, qbB = bx;
  const int q0A = qbA * 128 + w * 32, q0B = qbB * 128 + w * 32;
  const int ntA = (qbA + 1) * 2;
  const int kmaxA = (q0A + 31) >> 6, kmaxB = (q0B + 31) >> 6;

  // Q fragments (B-operand)
  bf16x8 qaA[2][2], qaB[2][2];
#pragma unroll
  for (int qc = 0; qc < 2; qc++)
#pragma unroll
    for (int kg = 0; kg < 2; kg++) {
      qaA[qc][kg] = ld16(qbase + (size_t)(q0A + qc * 16 + c16) * 2048
                               + h * 64 + kg * 32 + d8);
      qaB[qc][kg] = ld16(qbase + (size_t)(q0B + qc * 16 + c16) * 2048
                               + h * 64 + kg * 32 + d8);
    }

  const f32x4 zz = {0.f, 0.f, 0.f, 0.f};
  f32x4 oA[2][4], oB[2][4];
#pragma unroll
  for (int m = 0; m < 2; m++)
#pragma unroll
    for (int n = 0; n < 4; n++) { oA[m][n] = zz; oB[m][n] = zz; }
  float mA[2] = {-1e30f, -1e30f}, lA[2] = {0.f, 0.f};
  float mB[2] = {-1e30f, -1e30f}, lB[2] = {0.f, 0.f};

  auto STAGEK = [&](int t, int bufi) {
#pragma unroll
    for (int i = 0; i < 2; i++) {
      int row = i * 32 + kvr;
      int srcb = cb ^ ((row & 7) << 4);
      gload_lds16(kbase + (size_t)(t * 64 + row) * 2048 + (srcb >> 1),
                  &Ksh[bufi][i * 2048 + w * 512]);
    }
  };

  // QK^T: S^T[mt][qc] = K(rows kv) . Q^T(cols q), K from swizzled LDS
  auto QK = [&](const unsigned short* Kc, bf16x8 (&qa)[2][2], f32x4 (&st)[4][2]) {
    bf16x8 kb[4];
    int bo0 = ((d8) * 2) ^ ((c16 & 7) << 4);
    int bo1 = (((32 + d8)) * 2) ^ ((c16 & 7) << 4);
#pragma unroll
    for (int mt = 0; mt < 4; mt++)
      kb[mt] = ld16(Kc + (mt * 16 + c16) * 64 + (bo0 >> 1));
#pragma unroll
    for (int mt = 0; mt < 4; mt++)
#pragma unroll
      for (int qc = 0; qc < 2; qc++)
        st[mt][qc] = __builtin_amdgcn_mfma_f32_16x16x32_bf16(kb[mt], qa[qc][0], zz, 0, 0, 0);
#pragma unroll
    for (int mt = 0; mt < 4; mt++)
      kb[mt] = ld16(Kc + (mt * 16 + c16) * 64 + (bo1 >> 1));
#pragma unroll
    for (int mt = 0; mt < 4; mt++)
#pragma unroll
      for (int qc = 0; qc < 2; qc++)
        st[mt][qc] = __builtin_amdgcn_mfma_f32_16x16x32_bf16(kb[mt], qa[qc][1], st[mt][qc], 0, 0, 0);
  };

  // mask + online softmax (exp2 domain, defer-max) + P-write + PV
  auto SMPV = [&](f32x4 (&st)[4][2], f32x4 (&o)[2][4], float (&mrun)[2],
                  float (&lrun)[2], int q0, int kvt,
                  bf16x8 (&vb0)[4], bf16x8 (&vb1)[4]) {
    if (kvt * 64 + 63 > q0) {
#pragma unroll
      for (int mt = 0; mt < 4; mt++)
#pragma unroll
        for (int qc = 0; qc < 2; qc++) {
          int qg = q0 + qc * 16 + c16;
#pragma unroll
          for (int r = 0; r < 4; r++) {
            int kvg = kvt * 64 + mt * 16 + r4 + r;
            if (kvg > qg) st[mt][qc][r] = -1e30f;
          }
        }
    }
    float plane[2];
#pragma unroll
    for (int qc = 0; qc < 2; qc++) {
      float mx = -1e30f;
#pragma unroll
      for (int mt = 0; mt < 4; mt++)
#pragma unroll
        for (int r = 0; r < 4; r++) mx = fmaxf(mx, st[mt][qc][r]);
      plane[qc] = mx;
    }
    int defer0 = __all(plane[0] - mrun[0] <= 11.5f);
    int defer1 = __all(plane[1] - mrun[1] <= 11.5f);
    float scq[2] = {1.f, 1.f};
#pragma unroll
    for (int qc = 0; qc < 2; qc++) {
      int defer = qc ? defer1 : defer0;
      if (!defer) {
        float mx = plane[qc];
        mx = fmaxf(mx, __shfl_xor(mx, 16));
        mx = fmaxf(mx, __shfl_xor(mx, 32));
        float mn = fmaxf(mrun[qc], mx);
        scq[qc] = EXP2(mrun[qc] - mn);
        mrun[qc] = mn;
      }
      float mn = mrun[qc];
      float rs = 0.f;
#pragma unroll
      for (int mt = 0; mt < 4; mt++)
#pragma unroll
        for (int r = 0; r < 4; r++) {
          float p = EXP2(st[mt][qc][r] - mn);
          st[mt][qc][r] = p;
          rs += p;
        }
      rs += __shfl_xor(rs, 16);
      rs += __shfl_xor(rs, 32);
      lrun[qc] = lrun[qc] * scq[qc] + rs;
    }
    if (!(defer0 && defer1)) {
#pragma unroll
      for (int m = 0; m < 2; m++)
#pragma unroll
        for (int r = 0; r < 4; r++) {
          float sc = __shfl(scq[m], (l & 48) | (r4 + r));
#pragma unroll
          for (int n = 0; n < 4; n++) o[m][n][r] *= sc;
        }
    }
    // P^T -> per-wave slab, packed 8B swizzled stores
#pragma unroll
    for (int qc = 0; qc < 2; qc++) {
      int rowl = qc * 16 + c16;
#pragma unroll
      for (int mt = 0; mt < 4; mt++) {
        int byteoff = ((mt * 16 + r4) * 2) ^ ((c16 & 7) << 4);
        u16x4 pk;
#pragma unroll
        for (int r = 0; r < 4; r++) pk[r] = f2bf(st[mt][qc][r]);
        *(u16x4*)(Psw + rowl * 64 + (byteoff >> 1)) = pk;
      }
    }
    // O += P V
    bf16x8 pa[2];
    int bo0 = (d8 * 2) ^ ((c16 & 7) << 4);
    int bo1 = ((32 + d8) * 2) ^ ((c16 & 7) << 4);
#pragma unroll
    for (int m = 0; m < 2; m++)
      pa[m] = ld16(Psw + (m * 16 + c16) * 64 + (bo0 >> 1));
#pragma unroll
    for (int m = 0; m < 2; m++)
#pragma unroll
      for (int n = 0; n < 4; n++)
        o[m][n] = __builtin_amdgcn_mfma_f32_16x16x32_bf16(pa[m], vb0[n], o[m][n], 0, 0, 0);
#pragma unroll
    for (int m = 0; m < 2; m++)
      pa[m] = ld16(Psw + (m * 16 + c16) * 64 + (bo1 >> 1));
#pragma unroll
    for (int m = 0; m < 2; m++)
#pragma unroll
      for (int n = 0; n < 4; n++)
        o[m][n] = __builtin_amdgcn_mfma_f32_16x16x32_bf16(pa[m], vb1[n], o[m][n], 0, 0, 0);
  };

  STAGEK(0, 0);
  STAGEK(1, 1);
  asm volatile("s_waitcnt vmcnt(2)" ::: "memory");
  __builtin_amdgcn_s_barrier();

  int bufc = 0;
  for (int kvt = 0; kvt < ntA; kvt++) {
    const int bufn = bufc ? bufc - 1 : 2;       // (kvt+2) % 3
    const bool more = (kvt + 2 < ntA);
    if (more) STAGEK(kvt + 2, bufn);
    const unsigned short* Kc = Ksh[bufc];

    if (kvt <= kmaxA) {
      f32x4 st[4][2];
      QK(Kc, qaA, st);
      bf16x8 vb0[4], vb1[4];
#pragma unroll
      for (int n = 0; n < 4; n++) {
        vb0[n] = ld16(vbase + (size_t)(n * 16 + c16) * 1024 + kvt * 64 + d8);
        vb1[n] = ld16(vbase + (size_t)(n * 16 + c16) * 1024 + kvt * 64 + 32 + d8);
      }
      SMPV(st, oA, mA, lA, q0A, kvt, vb0, vb1);
      if (kvt <= kmaxB) {
        QK(Kc, qaB, st);
        SMPV(st, oB, mB, lB, q0B, kvt, vb0, vb1);
      }
    }

    if (more) asm volatile("s_waitcnt vmcnt(2)" ::: "memory");
    else      asm volatile("s_waitcnt vmcnt(0)" ::: "memory");
    __builtin_amdgcn_s_barrier();
    bufc = (bufc == 2) ? 0 : bufc + 1;
  }

  // epilogues: broadcast 1/l into O layout, write ctx [b][s][h*64+d]
  auto WRITE = [&](f32x4 (&o)[2][4], float (&lrun)[2], int q0) {
    float invq[2];
#pragma unroll
    for (int qc = 0; qc < 2; qc++) invq[qc] = 1.f / lrun[qc];
#pragma unroll
    for (int m = 0; m < 2; m++)
#pragma unroll
      for (int r = 0; r < 4; r++) {
        float inv = __shfl(invq[m], (l & 48) | (r4 + r));
        int qg = q0 + m * 16 + r4 + r;
#pragma unroll
        for (int n = 0; n < 4; n++) {
          int d = n * 16 + c16;
          ctx[(size_t)(b * SEQ + qg) * DM + h * 64 + d] = f2bf(o[m][n][r] * inv);
        }
      }
  };
  WRITE(oA, lA, q0A);
  WRITE(oB, lB, q0B);
}

extern "C" void kernel_launch(void* const* d_in, const int* in_sizes, int n_in,
                              void* d_out, int out_size, void* d_ws, size_t ws_size,
                              hipStream_t stream)
{
  const float* x     = (const float*)d_in[0];
  const float* qkv_w = (const float*)d_in[1];
  const float* qkv_b = (const float*)d_in[2];
  const float* out_w = (const float*)d_in[3];
  const float* out_b = (const float*)d_in[4];

  unsigned short* ws   = (unsigned short*)d_ws;
  unsigned short* xb   = ws;                          // 8192*1024
  unsigned short* wqT  = xb  + (size_t)8192 * 1024;   // 3072*1024
  unsigned short* woT  = wqT + 3072 * 1024;           // 1024*1024
  unsigned short* qkb  = woT + 1024 * 1024;           // 8192*2048 (Q|K)
  unsigned short* vTb  = qkb + (size_t)8192 * 2048;   // 128*64*1024 (V^T)
  unsigned short* ctxb = vTb + (size_t)128 * 64 * 1024; // 8192*1024  (~88 MB total)

  hipLaunchKernelGGL(cvt_f32_bf16, dim3(8192 * 1024 / 8 / 256), dim3(256), 0, stream,
                     x, xb, 8192 * 1024);
  hipLaunchKernelGGL(transpose_cvt, dim3(3072 / 32, 1024 / 32), dim3(32, 8), 0, stream,
                     qkv_w, wqT, 1024, 3072);
  hipLaunchKernelGGL(transpose_cvt, dim3(1024 / 32, 1024 / 32), dim3(32, 8), 0, stream,
                     out_w, woT, 1024, 1024);
  hipLaunchKernelGGL(gemm_bt<1>, dim3(64 * 24), dim3(256), 0, stream,
                     xb, wqT, qkv_b, (void*)qkb, vTb, 8192, 3072, 1024);
  hipLaunchKernelGGL(attn, dim3(4, 128), dim3(256), 0, stream,
                     qkb, vTb, ctxb);
  hipLaunchKernelGGL(gemm_bt<2>, dim3(64 * 8), dim3(256), 0, stream,
                     ctxb, woT, out_b, d_out, nullptr, 8192, 1024, 1024);
}